// Round 11
// baseline (471.198 us; speedup 1.0000x reference)
//
#include <hip/hip_runtime.h>
#include <cstdint>
#include <cstddef>

// ============================================================================
// VQ-VAE encode: conv3x3(SAME) -> linear (folded) -> argmin over 8192 codes.
//
// Round 21: convm9 = 8-wave conv (2 waves/SIMD intra-block overlap);
//   screen QUARTERED for per-kernel counter visibility.
//   R20 ledger: non-screen bucket = 295us but top-5 only ever shows the
//   argmax kernel (5 iterations) -> convm8's dur unknown; 3 of last 5
//   rounds were blind conv edits. Two moves:
//   (1) convm9_k: convm6's counters (MfmaUtil 40%, Occ 10.7%) say 1 wave/
//       SIMD serializes ~930cyc MFMA with ~750cyc LDS reads per phase.
//       8-wave 128x256 tile (2x4 of 64x64) + z-split cc-halves (grid 128x2,
//       72 phases): 2 waves/SIMD overlap MFMA with ds_reads inside each
//       phase (m114). LDS 96KB: A dbuf 2x16K | B dbuf 2x32K. Per-output
//       MFMA order bit-identical to convm6/8 (pack3 sums z-halves; proven).
//   (2) screen11 -> 4 x 1024-block dispatches (off-mechanism proven R18):
//       +~25us ramp/drain, buys counters on the true argmax next round.
// argmin tie-break everywhere: strict < with smaller-index preference.
// ============================================================================

#define CIN_  512
#define E_    4608
#define M_    16384

typedef _Float16 half4_t __attribute__((ext_vector_type(4)));
typedef _Float16 half8_t __attribute__((ext_vector_type(8)));
typedef float f32x4 __attribute__((ext_vector_type(4)));

#define GLOAD_LDS16(gptr, lptr)                                         \
    __builtin_amdgcn_global_load_lds(                                   \
        (const __attribute__((address_space(1))) unsigned int*)(gptr),  \
        (__attribute__((address_space(3))) unsigned int*)(lptr), 16, 0, 0)

// ---------------- fused prologue: packlat | fold5-direct | bias-direct -----
// grid 833 x 256 thr. blocks 0..255: latent->Xnp pack. blocks 256..831: W2x
// fold for e0=(bb-256)*8 via LDS-transposed lin_w chunks. block 832: bias.
__global__ __launch_bounds__(256) void prep_k(
    const float* __restrict__ lat, const float* __restrict__ lin_w,
    const float* __restrict__ conv_w, const float* __restrict__ conv_b,
    const float* __restrict__ lin_b,
    _Float16* __restrict__ Xnp, _Float16* __restrict__ W2x,
    float* __restrict__ b2) {
    __shared__ float ls[8448];              // 33792 B: lt[128][65] / lw[256][33]
    int bb = blockIdx.x, t = threadIdx.x;

    if (bb < 256) {
        float (*lt)[65] = (float(*)[65])ls;
        const float* src = lat + (size_t)bb * 512 * 64;
        _Float16* dst = Xnp + (size_t)bb * 64 * 1024;
        for (int c0 = 0; c0 < 512; c0 += 128) {
            __syncthreads();
            #pragma unroll
            for (int j = 0; j < 8; ++j) {
                int f4 = t + j * 256;
                int cc = f4 >> 4, p4 = (f4 & 15) * 4;
                float4 v = *(const float4*)(src + (size_t)(c0 + cc) * 64 + p4);
                lt[cc][p4] = v.x; lt[cc][p4 + 1] = v.y;
                lt[cc][p4 + 2] = v.z; lt[cc][p4 + 3] = v.w;
            }
            __syncthreads();
            int pix = t >> 2, cr = (t & 3) * 32;
            #pragma unroll
            for (int q = 0; q < 4; ++q) {
                half8_t hh, ll;
                #pragma unroll
                for (int j = 0; j < 8; ++j) {
                    float v = lt[cr + q * 8 + j][pix];
                    _Float16 h = (_Float16)v;
                    hh[j] = h; ll[j] = (_Float16)(v - (float)h);
                }
                *(half8_t*)(dst + (size_t)pix * 1024 + c0 + cr + q * 8) = hh;
                *(half8_t*)(dst + (size_t)pix * 1024 + 512 + c0 + cr + q * 8) = ll;
            }
        }
    } else if (bb < 832) {
        float (*lw)[33] = (float(*)[33])ls;
        int e0 = (bb - 256) * 8;
        int d = t;
        float acc[8];
        #pragma unroll
        for (int j = 0; j < 8; ++j) acc[j] = 0.f;
        for (int c0 = 0; c0 < 256; c0 += 32) {
            __syncthreads();
            #pragma unroll
            for (int k = 0; k < 8; ++k) {
                int f4 = t + k * 256;
                int row = f4 >> 3, c4 = (f4 & 7) * 4;
                float4 v = *(const float4*)(lin_w + (size_t)row * 256 + c0 + c4);
                lw[row][c4] = v.x; lw[row][c4 + 1] = v.y;
                lw[row][c4 + 2] = v.z; lw[row][c4 + 3] = v.w;
            }
            __syncthreads();
            for (int cp = 0; cp < 32; ++cp) {          // co ascending: bit-identical
                float lwv = lw[d][cp];
                const float* cwr = conv_w + (size_t)(c0 + cp) * E_ + e0;
                #pragma unroll
                for (int j = 0; j < 8; ++j) acc[j] += cwr[j] * lwv;
            }
        }
        #pragma unroll
        for (int j = 0; j < 8; ++j) {
            int e = e0 + j;
            int c = e / 9, t9 = e - c * 9;
            _Float16 h = (_Float16)acc[j];
            _Float16 l = (_Float16)(acc[j] - (float)h);
            W2x[((size_t)(t9 * 256 + d)) * 512 + c] = h;
            W2x[((size_t)((9 + t9) * 256 + d)) * 512 + c] = l;
        }
    } else {
        float (*lw)[33] = (float(*)[33])ls;
        int d = t;
        float acc = lin_b[d];
        for (int c0 = 0; c0 < 256; c0 += 32) {
            __syncthreads();
            #pragma unroll
            for (int k = 0; k < 8; ++k) {
                int f4 = t + k * 256;
                int row = f4 >> 3, c4 = (f4 & 7) * 4;
                float4 v = *(const float4*)(lin_w + (size_t)row * 256 + c0 + c4);
                lw[row][c4] = v.x; lw[row][c4 + 1] = v.y;
                lw[row][c4 + 2] = v.z; lw[row][c4 + 3] = v.w;
            }
            __syncthreads();
            for (int cp = 0; cp < 32; ++cp) acc += lw[d][cp] * conv_b[c0 + cp];
        }
        b2[d] = acc;
    }
}

// ---------------- conv MFMA v9: 8-wave 128x256 tile, z-split cc-halves -----
// grid (128 m-tiles, 2 cc-halves) = 256 blocks, 512 thr = 8 waves (2 wm x
// 4 wn of 64x64) -> 2 waves/SIMD: MFMA overlaps ds_reads within each phase.
// 72 phases (8 cc x 9 taps). LDS 96 KB: A dbuf 2x{Ah 8K,Al 8K} @0 |
// B dbuf 2x{Bh 16K,Bl 16K} @32768. y=0: yb = p0 + bias; y=1: tmp = p1.
// Per-output MFMA order identical to convm6/convm8.
__global__ __launch_bounds__(512) void convm9_k(
    const _Float16* __restrict__ Xnp, const _Float16* __restrict__ W2x,
    const float* __restrict__ b2, float* __restrict__ yb,
    float* __restrict__ tmp) {
    __shared__ char sm[98304];
    int m0 = blockIdx.x * 128;
    int cc0 = blockIdx.y * 8;
    int tid = threadIdx.x, w = tid >> 6, lane = tid & 63;
    int wm = w & 1, wn = w >> 2;           // 2 x 4 wave grid (w = wm + 2*wn')
    wn = (w >> 1);                          // waves: wm = w&1, wn = w>>1 in 0..3
    int fr = lane & 15, fq = lane >> 4;

    int xq = (fq ^ ((fr >> 1) & 3)) << 4;
    int boff[4];
    #pragma unroll
    for (int i = 0; i < 4; ++i) boff[i] = (wn * 64 + i * 16 + fr) * 64 + xq;
    int imgoff[4], ph[4], pw[4];
    #pragma unroll
    for (int s = 0; s < 4; ++s) {
        int rr = wm * 64 + s * 16 + fr;
        imgoff[s] = rr & 64; ph[s] = (rr >> 3) & 7; pw[s] = rr & 7;
    }
    // staging: A 1 granule/thr/plane (8 KB); B 2 granules/thr/plane (16 KB)
    int sAr = tid >> 2, sAq = ((tid & 3) ^ ((tid >> 3) & 3)) * 8;
    int sBs[2], sBr[2], sBq[2];
    #pragma unroll
    for (int i = 0; i < 2; ++i) {
        int s = i * 512 + tid;
        sBs[i] = s;
        sBr[i] = s >> 2;
        sBq[i] = ((s & 3) ^ ((s >> 3) & 3)) * 8;
    }

    auto stageA = [&](int cc, int buf) {
        char* L = sm + buf * 16384;
        const _Float16* base =
            Xnp + (size_t)(m0 + sAr) * 1024 + cc * 32 + sAq;
        GLOAD_LDS16(base, L + tid * 16);               // hi plane 8K
        GLOAD_LDS16(base + 512, L + 8192 + tid * 16);  // lo plane 8K
    };
    auto stageB = [&](int tap, int cc, int buf) {
        char* L = sm + 32768 + buf * 32768;
        #pragma unroll
        for (int i = 0; i < 2; ++i) {
            const _Float16* bb =
                W2x + ((size_t)(tap * 256 + sBr[i])) * 512 + cc * 32 + sBq[i];
            GLOAD_LDS16(bb, L + sBs[i] * 16);                        // Bh 16K
            GLOAD_LDS16(bb + (size_t)9 * 256 * 512, L + 16384 + sBs[i] * 16);
        }
    };

    f32x4 acc[4][4];
    #pragma unroll
    for (int s = 0; s < 4; ++s)
        #pragma unroll
        for (int t = 0; t < 4; ++t)
            #pragma unroll
            for (int r = 0; r < 4; ++r) acc[s][t][r] = 0.f;

    stageA(cc0, 0);
    stageB(0, cc0, 0);
    const half8_t zfrag = {};
    int gi = 0;
    for (int cci = 0; cci < 8; ++cci) {
        int cc = cc0 + cci;
        const char* Ab = sm + (cci & 1) * 16384;
        for (int tap = 0; tap < 9; ++tap, ++gi) {
            __syncthreads();
            if (tap < 8) stageB(tap + 1, cc, (gi + 1) & 1);
            else if (cci < 7) stageB(0, cc + 1, (gi + 1) & 1);
            if (tap == 7 && cci < 7) stageA(cc + 1, (cci + 1) & 1);

            int dy = tap / 3 - 1, dx = tap - (tap / 3) * 3 - 1;
            half8_t ah[4], al[4];
            #pragma unroll
            for (int s = 0; s < 4; ++s) {
                int ih = ph[s] + dy, iw = pw[s] + dx;
                bool v = ((unsigned)ih < 8u) && ((unsigned)iw < 8u);
                int pp = imgoff[s] + (v ? ih * 8 + iw : 0);
                int ao = pp * 64 + ((fq ^ ((pp >> 1) & 3)) << 4);
                half8_t a0 = *(const half8_t*)(Ab + ao);
                half8_t a1 = *(const half8_t*)(Ab + 8192 + ao);
                ah[s] = v ? a0 : zfrag;
                al[s] = v ? a1 : zfrag;
            }
            const char* Bb = sm + 32768 + (gi & 1) * 32768;
            half8_t bh[4], bl[4];
            #pragma unroll
            for (int t = 0; t < 4; ++t) {
                bh[t] = *(const half8_t*)(Bb + boff[t]);
                bl[t] = *(const half8_t*)(Bb + 16384 + boff[t]);
            }
            #pragma unroll
            for (int s = 0; s < 4; ++s)
                #pragma unroll
                for (int t = 0; t < 4; ++t)
                    acc[s][t] = __builtin_amdgcn_mfma_f32_16x16x32_f16(
                        ah[s], bh[t], acc[s][t], 0, 0, 0);
            #pragma unroll
            for (int s = 0; s < 4; ++s)
                #pragma unroll
                for (int t = 0; t < 4; ++t)
                    acc[s][t] = __builtin_amdgcn_mfma_f32_16x16x32_f16(
                        ah[s], bl[t], acc[s][t], 0, 0, 0);
            #pragma unroll
            for (int s = 0; s < 4; ++s)
                #pragma unroll
                for (int t = 0; t < 4; ++t)
                    acc[s][t] = __builtin_amdgcn_mfma_f32_16x16x32_f16(
                        al[s], bh[t], acc[s][t], 0, 0, 0);
        }
    }

    // epilogue: y=0 -> yb (+bias); y=1 -> tmp (raw partial)
    float* dst = (blockIdx.y == 0) ? yb : tmp;
    float bv[4];
    #pragma unroll
    for (int t = 0; t < 4; ++t)
        bv[t] = (blockIdx.y == 0) ? b2[wn * 64 + t * 16 + fr] : 0.f;
    #pragma unroll
    for (int s = 0; s < 4; ++s)
        #pragma unroll
        for (int r = 0; r < 4; ++r) {
            int m = m0 + wm * 64 + s * 16 + fq * 4 + r;
            #pragma unroll
            for (int t = 0; t < 4; ++t) {
                int d = wn * 64 + t * 16 + fr;
                dst[(size_t)m * 256 + d] = acc[s][t][r] + bv[t];
            }
        }
}

// ---------------- fused post-conv pack: yb += tmp; A2<-yb; B2,esq<-emb -----
__global__ __launch_bounds__(256) void pack3_k(
    float* __restrict__ yb, const float* __restrict__ tmp,
    const float* __restrict__ emb,
    _Float16* __restrict__ A2, _Float16* __restrict__ B2,
    float* __restrict__ esq) {
    #pragma unroll
    for (int it = 0; it < 8; ++it) {
        int i = (blockIdx.x + it * 512) * 256 + threadIdx.x;
        float4 v = *(const float4*)(yb + (size_t)i * 4);
        float4 t = *(const float4*)(tmp + (size_t)i * 4);
        float4 s = {v.x + t.x, v.y + t.y, v.z + t.z, v.w + t.w};
        *(float4*)(yb + (size_t)i * 4) = s;
        half4_t h = {(_Float16)s.x, (_Float16)s.y, (_Float16)s.z, (_Float16)s.w};
        *(half4_t*)(A2 + (size_t)i * 4) = h;
    }
    int w = threadIdx.x >> 6, lane = threadIdx.x & 63;
    #pragma unroll
    for (int j = 0; j < 4; ++j) {
        int k = blockIdx.x * 16 + w * 4 + j;
        float4 v = *(const float4*)(emb + (size_t)k * 256 + lane * 4);
        half4_t h = {(_Float16)v.x, (_Float16)v.y, (_Float16)v.z, (_Float16)v.w};
        *(half4_t*)(B2 + (size_t)k * 256 + lane * 4) = h;
        float s = v.x * v.x + v.y * v.y + v.z * v.z + v.w * v.w;
        #pragma unroll
        for (int m = 32; m >= 1; m >>= 1) s += __shfl_xor(s, m, 64);
        if (lane == 0) esq[k] = s;
    }
}

// ---------------- MFMA screen v11q: R15 math, block-offset quarters --------
// Launched 4 x 1024 blocks (off 0,1024,2048,3072) for top-5 visibility of
// the mid-size kernels. Per-block math identical to R15 winner (absmax 0).
__global__ __launch_bounds__(512) void screen11_k(
    const _Float16* __restrict__ A2, const _Float16* __restrict__ B2,
    const float* __restrict__ esq, float* __restrict__ ps2, int* __restrict__ pi2,
    int off) {
    __shared__ char sm[49152];
    int Lb = blockIdx.x + off;
    int xcd = Lb & 7, j = Lb >> 3;
    int mt = xcd * 16 + (j & 15);
    int nt = j >> 4;
    int m0 = mt * 128, n0 = nt * 256;
    int tid = threadIdx.x, w = tid >> 6, lane = tid & 63;
    int wm = w & 1, wn = w >> 1;
    int fr = lane & 15, fq = lane >> 4;

    int xq = (fq ^ ((fr >> 1) & 3)) << 4;
    int aoff[4], boff[4];
    #pragma unroll
    for (int i = 0; i < 4; ++i) {
        aoff[i] = (wm * 64 + i * 16 + fr) * 64 + xq;
        boff[i] = (wn * 64 + i * 16 + fr) * 64 + xq;
    }
    int sAr = tid >> 2, sAq = ((tid & 3) ^ ((tid >> 3) & 3)) * 8;
    int sBs[2], sBr[2], sBq[2];
    #pragma unroll
    for (int i = 0; i < 2; ++i) {
        int s = i * 512 + tid;
        sBs[i] = s;
        sBr[i] = s >> 2;
        sBq[i] = ((s & 3) ^ ((s >> 3) & 3)) * 8;
    }

    auto stage = [&](int kt, int buf) {
        char* L = sm + buf * 24576;
        int ko = kt * 32;
        GLOAD_LDS16(A2 + (size_t)(m0 + sAr) * 256 + ko + sAq, L + tid * 16);
        #pragma unroll
        for (int i = 0; i < 2; ++i)
            GLOAD_LDS16(B2 + (size_t)(n0 + sBr[i]) * 256 + ko + sBq[i],
                        L + 8192 + sBs[i] * 16);
    };

    f32x4 acc[4][4];
    #pragma unroll
    for (int s = 0; s < 4; ++s)
        #pragma unroll
        for (int t = 0; t < 4; ++t)
            #pragma unroll
            for (int r = 0; r < 4; ++r) acc[s][t][r] = 0.f;

    stage(0, 0);
    for (int kt = 0; kt < 8; ++kt) {
        __syncthreads();
        if (kt + 1 < 8) stage(kt + 1, (kt + 1) & 1);
        const char* L = sm + (kt & 1) * 24576;
        half8_t af[4], bf[4];
        #pragma unroll
        for (int s = 0; s < 4; ++s) af[s] = *(const half8_t*)(L + aoff[s]);
        #pragma unroll
        for (int t = 0; t < 4; ++t) bf[t] = *(const half8_t*)(L + 8192 + boff[t]);
        #pragma unroll
        for (int s = 0; s < 4; ++s)
            #pragma unroll
            for (int t = 0; t < 4; ++t)
                acc[s][t] = __builtin_amdgcn_mfma_f32_16x16x32_f16(
                    af[s], bf[t], acc[s][t], 0, 0, 0);
    }

    float esv[4];
    #pragma unroll
    for (int t = 0; t < 4; ++t) esv[t] = esq[n0 + wn * 64 + t * 16 + fr];
    int colIdx = nt * 4 + wn;
    #pragma unroll
    for (int s = 0; s < 4; ++s) {
        #pragma unroll
        for (int r = 0; r < 4; ++r) {
            float best = 3.4e38f; int bidx = 0x7fffffff;
            #pragma unroll
            for (int t = 0; t < 4; ++t) {
                float sc = esv[t] - 2.f * acc[s][t][r];
                int k = n0 + wn * 64 + t * 16 + fr;
                if (sc < best || (sc == best && k < bidx)) { best = sc; bidx = k; }
            }
            #pragma unroll
            for (int msk = 1; msk <= 8; msk <<= 1) {
                float so = __shfl_xor(best, msk, 64);
                int ko2 = __shfl_xor(bidx, msk, 64);
                if (so < best || (so == best && ko2 < bidx)) { best = so; bidx = ko2; }
            }
            if (fr == 0) {
                int m = m0 + wm * 64 + s * 16 + fq * 4 + r;
                ps2[(size_t)m * 128 + colIdx] = best;
                pi2[(size_t)m * 128 + colIdx] = bidx;
            }
        }
    }
}

// ---------------- exact fp32 refine, grid-stride (512 blocks) ----------------
__global__ __launch_bounds__(256) void refine3_k(
    const float* __restrict__ y, const float* __restrict__ emb,
    const float* __restrict__ esq, const float* __restrict__ ps2,
    const int* __restrict__ pi2, int* __restrict__ out) {
    int lane = threadIdx.x & 63;
    for (int j = 0; j < 8; ++j) {
        int m = blockIdx.x * 32 + j * 4 + (threadIdx.x >> 6);
        float4 yv = *(const float4*)(y + (size_t)m * 256 + lane * 4);
        float sc_[2]; int kc_[2];
        #pragma unroll
        for (int i = 0; i < 2; ++i) {
            sc_[i] = ps2[(size_t)m * 128 + lane * 2 + i];
            kc_[i] = pi2[(size_t)m * 128 + lane * 2 + i];
        }
        float s0 = fminf(sc_[0], sc_[1]);
        #pragma unroll
        for (int msk = 1; msk <= 32; msk <<= 1) s0 = fminf(s0, __shfl_xor(s0, msk, 64));
        float thr = s0 + 0.25f;
        float best = 3.4e38f; int bk = 0x7fffffff;
        for (int c = 0; c < 128; ++c) {
            float scc = __shfl(sc_[c & 1], c >> 1, 64);
            if (scc <= thr) {            // wave-uniform
                int k = __shfl(kc_[c & 1], c >> 1, 64);
                float4 ev = *(const float4*)(emb + (size_t)k * 256 + lane * 4);
                float d = yv.x * ev.x + yv.y * ev.y + yv.z * ev.z + yv.w * ev.w;
                #pragma unroll
                for (int msk = 1; msk <= 32; msk <<= 1) d += __shfl_xor(d, msk, 64);
                float sx = esq[k] - 2.f * d;
                if (sx < best || (sx == best && k < bk)) { best = sx; bk = k; }
            }
        }
        if (lane == 0) out[m] = bk;
    }
}

extern "C" void kernel_launch(void* const* d_in, const int* in_sizes, int n_in,
                              void* d_out, int out_size, void* d_ws, size_t ws_size,
                              hipStream_t stream) {
    const float* latent = (const float*)d_in[0];
    const float* conv_w = (const float*)d_in[1];
    const float* conv_b = (const float*)d_in[2];
    const float* lin_w  = (const float*)d_in[3];
    const float* lin_b  = (const float*)d_in[4];
    const float* emb    = (const float*)d_in[5];
    int* out = (int*)d_out;

    char* W = (char*)d_ws;                           // proven 55.35 MB budget
    float*    b2  = (float*)(W + 262144);            //     1,024
    float*    esq = (float*)(W + 263168);            //    32,768
    float*    yb  = (float*)(W + 295936);            // 16,777,216
    _Float16* W2x = (_Float16*)(W + 17073152);       //  4,718,592
    _Float16* Xnp = (_Float16*)(W + 21792768);       // 33,554,432 (live: prep -> convm9)
    // post-conv aliases on the (dead) Xnp region:
    _Float16* A2  = (_Float16*)(W + 21792768);       //  8,388,608 (pack3 -> screen11)
    _Float16* B2  = (_Float16*)(W + 30181376);       //  4,194,304 (pack3 -> screen11)
    float*    ps2 = (float*)(W + 34375680);          //  8,388,608 (screen11 -> refine3)
    int*      pi2 = (int*)(W + 42764288);            //  8,388,608 -> ends 51,152,896
    // conv partial-sum half 2: occupies the (pre-screen dead) ps2+pi2 span
    float*    tmp = (float*)(W + 34375680);          // 16,777,216 (convm9 -> pack3)

    prep_k<<<833, 256, 0, stream>>>(latent, lin_w, conv_w, conv_b, lin_b,
                                    Xnp, W2x, b2);
    convm9_k<<<dim3(128, 2), 512, 0, stream>>>(Xnp, W2x, b2, yb, tmp);
    pack3_k<<<512, 256, 0, stream>>>(yb, tmp, emb, A2, B2, esq);  // Xnp, tmp dead after
    screen11_k<<<1024, 512, 0, stream>>>(A2, B2, esq, ps2, pi2, 0);
    screen11_k<<<1024, 512, 0, stream>>>(A2, B2, esq, ps2, pi2, 1024);
    screen11_k<<<1024, 512, 0, stream>>>(A2, B2, esq, ps2, pi2, 2048);
    screen11_k<<<1024, 512, 0, stream>>>(A2, B2, esq, ps2, pi2, 3072);
    refine3_k<<<512, 256, 0, stream>>>(yb, emb, esq, ps2, pi2, out);
}

// Round 12
// 433.108 us; speedup vs baseline: 1.0879x; 1.0879x over previous
//
#include <hip/hip_runtime.h>
#include <cstdint>
#include <cstddef>

// ============================================================================
// VQ-VAE encode: conv3x3(SAME) -> linear (folded) -> argmin over 8192 codes.
//
// Round 22: convm10 = convm9 + XCD-partitioned cc-halves; screen un-quartered.
//   R21 counters (convm9 96.6us, MfmaUtil 54%, 1 block/CU): per-phase 3220cyc
//   vs ~1850 modeled. Diagnosis: B-restage = 256 blocks x 72 x 32KB = 590MB/
//   dispatch; W2x (4.7MB) > per-XCD L2 (4MiB) with default round-robin
//   mapping (both cc-halves demanded on every XCD) -> staging served by L3
//   (~6TB/s ~ 85us) -> conv is L3-BW-bound.
//   Fix: 1-D grid 256, xcd = Lb&7; XCDs 0-3 own z=0 (cc 0-7), XCDs 4-7 own
//   z=1 (cc 8-15); mt = (xcd&3)*32 + (Lb>>3). Per-XCD W2x slice = 2.36MB
//   <= 4MiB -> B staging hits XCD-L2 (~17us for 590MB). Per-block math
//   bit-identical (decode-only change; absmax-0 lineage).
//   screen11: single 4096-block dispatch (R15 winner, 145.5us proven);
//   the R21 quartering was measurement-only (+~25us) and is removed.
// argmin tie-break everywhere: strict < with smaller-index preference.
// ============================================================================

#define CIN_  512
#define E_    4608
#define M_    16384

typedef _Float16 half4_t __attribute__((ext_vector_type(4)));
typedef _Float16 half8_t __attribute__((ext_vector_type(8)));
typedef float f32x4 __attribute__((ext_vector_type(4)));

#define GLOAD_LDS16(gptr, lptr)                                         \
    __builtin_amdgcn_global_load_lds(                                   \
        (const __attribute__((address_space(1))) unsigned int*)(gptr),  \
        (__attribute__((address_space(3))) unsigned int*)(lptr), 16, 0, 0)

// ---------------- fused prologue: packlat | fold5-direct | bias-direct -----
// grid 833 x 256 thr. blocks 0..255: latent->Xnp pack. blocks 256..831: W2x
// fold for e0=(bb-256)*8 via LDS-transposed lin_w chunks. block 832: bias.
__global__ __launch_bounds__(256) void prep_k(
    const float* __restrict__ lat, const float* __restrict__ lin_w,
    const float* __restrict__ conv_w, const float* __restrict__ conv_b,
    const float* __restrict__ lin_b,
    _Float16* __restrict__ Xnp, _Float16* __restrict__ W2x,
    float* __restrict__ b2) {
    __shared__ float ls[8448];              // 33792 B: lt[128][65] / lw[256][33]
    int bb = blockIdx.x, t = threadIdx.x;

    if (bb < 256) {
        float (*lt)[65] = (float(*)[65])ls;
        const float* src = lat + (size_t)bb * 512 * 64;
        _Float16* dst = Xnp + (size_t)bb * 64 * 1024;
        for (int c0 = 0; c0 < 512; c0 += 128) {
            __syncthreads();
            #pragma unroll
            for (int j = 0; j < 8; ++j) {
                int f4 = t + j * 256;
                int cc = f4 >> 4, p4 = (f4 & 15) * 4;
                float4 v = *(const float4*)(src + (size_t)(c0 + cc) * 64 + p4);
                lt[cc][p4] = v.x; lt[cc][p4 + 1] = v.y;
                lt[cc][p4 + 2] = v.z; lt[cc][p4 + 3] = v.w;
            }
            __syncthreads();
            int pix = t >> 2, cr = (t & 3) * 32;
            #pragma unroll
            for (int q = 0; q < 4; ++q) {
                half8_t hh, ll;
                #pragma unroll
                for (int j = 0; j < 8; ++j) {
                    float v = lt[cr + q * 8 + j][pix];
                    _Float16 h = (_Float16)v;
                    hh[j] = h; ll[j] = (_Float16)(v - (float)h);
                }
                *(half8_t*)(dst + (size_t)pix * 1024 + c0 + cr + q * 8) = hh;
                *(half8_t*)(dst + (size_t)pix * 1024 + 512 + c0 + cr + q * 8) = ll;
            }
        }
    } else if (bb < 832) {
        float (*lw)[33] = (float(*)[33])ls;
        int e0 = (bb - 256) * 8;
        int d = t;
        float acc[8];
        #pragma unroll
        for (int j = 0; j < 8; ++j) acc[j] = 0.f;
        for (int c0 = 0; c0 < 256; c0 += 32) {
            __syncthreads();
            #pragma unroll
            for (int k = 0; k < 8; ++k) {
                int f4 = t + k * 256;
                int row = f4 >> 3, c4 = (f4 & 7) * 4;
                float4 v = *(const float4*)(lin_w + (size_t)row * 256 + c0 + c4);
                lw[row][c4] = v.x; lw[row][c4 + 1] = v.y;
                lw[row][c4 + 2] = v.z; lw[row][c4 + 3] = v.w;
            }
            __syncthreads();
            for (int cp = 0; cp < 32; ++cp) {          // co ascending: bit-identical
                float lwv = lw[d][cp];
                const float* cwr = conv_w + (size_t)(c0 + cp) * E_ + e0;
                #pragma unroll
                for (int j = 0; j < 8; ++j) acc[j] += cwr[j] * lwv;
            }
        }
        #pragma unroll
        for (int j = 0; j < 8; ++j) {
            int e = e0 + j;
            int c = e / 9, t9 = e - c * 9;
            _Float16 h = (_Float16)acc[j];
            _Float16 l = (_Float16)(acc[j] - (float)h);
            W2x[((size_t)(t9 * 256 + d)) * 512 + c] = h;
            W2x[((size_t)((9 + t9) * 256 + d)) * 512 + c] = l;
        }
    } else {
        float (*lw)[33] = (float(*)[33])ls;
        int d = t;
        float acc = lin_b[d];
        for (int c0 = 0; c0 < 256; c0 += 32) {
            __syncthreads();
            #pragma unroll
            for (int k = 0; k < 8; ++k) {
                int f4 = t + k * 256;
                int row = f4 >> 3, c4 = (f4 & 7) * 4;
                float4 v = *(const float4*)(lin_w + (size_t)row * 256 + c0 + c4);
                lw[row][c4] = v.x; lw[row][c4 + 1] = v.y;
                lw[row][c4 + 2] = v.z; lw[row][c4 + 3] = v.w;
            }
            __syncthreads();
            for (int cp = 0; cp < 32; ++cp) acc += lw[d][cp] * conv_b[c0 + cp];
        }
        b2[d] = acc;
    }
}

// ---------------- conv MFMA v10: convm9 + XCD-partitioned cc-halves --------
// 1-D grid 256, 512 thr = 8 waves (2 wm x 4 wn of 64x64), 2 waves/SIMD.
// Decode: xcd = Lb&7; z = xcd>>2 (cc-half); mt = (xcd&3)*32 + (Lb>>3).
// Per-XCD W2x working set = 2.36MB <= 4MiB L2 -> B staging L2-resident.
// 72 phases (8 cc x 9 taps). LDS 96 KB: A dbuf 2x{Ah 8K,Al 8K} @0 |
// B dbuf 2x{Bh 16K,Bl 16K} @32768. z=0: yb = p0 + bias; z=1: tmp = p1.
// Per-output MFMA order identical to convm6/8/9.
__global__ __launch_bounds__(512) void convm10_k(
    const _Float16* __restrict__ Xnp, const _Float16* __restrict__ W2x,
    const float* __restrict__ b2, float* __restrict__ yb,
    float* __restrict__ tmp) {
    __shared__ char sm[98304];
    int Lb = blockIdx.x;
    int xcd = Lb & 7;
    int z = xcd >> 2;                       // cc-half: XCDs 0-3 -> 0, 4-7 -> 1
    int mt = (xcd & 3) * 32 + (Lb >> 3);    // 0..127, each (z,mt) exactly once
    int m0 = mt * 128;
    int cc0 = z * 8;
    int tid = threadIdx.x, w = tid >> 6, lane = tid & 63;
    int wm = w & 1, wn = w >> 1;            // 2 x 4 wave grid
    int fr = lane & 15, fq = lane >> 4;

    int xq = (fq ^ ((fr >> 1) & 3)) << 4;
    int boff[4];
    #pragma unroll
    for (int i = 0; i < 4; ++i) boff[i] = (wn * 64 + i * 16 + fr) * 64 + xq;
    int imgoff[4], ph[4], pw[4];
    #pragma unroll
    for (int s = 0; s < 4; ++s) {
        int rr = wm * 64 + s * 16 + fr;
        imgoff[s] = rr & 64; ph[s] = (rr >> 3) & 7; pw[s] = rr & 7;
    }
    // staging: A 1 granule/thr/plane (8 KB); B 2 granules/thr/plane (16 KB)
    int sAr = tid >> 2, sAq = ((tid & 3) ^ ((tid >> 3) & 3)) * 8;
    int sBs[2], sBr[2], sBq[2];
    #pragma unroll
    for (int i = 0; i < 2; ++i) {
        int s = i * 512 + tid;
        sBs[i] = s;
        sBr[i] = s >> 2;
        sBq[i] = ((s & 3) ^ ((s >> 3) & 3)) * 8;
    }

    auto stageA = [&](int cc, int buf) {
        char* L = sm + buf * 16384;
        const _Float16* base =
            Xnp + (size_t)(m0 + sAr) * 1024 + cc * 32 + sAq;
        GLOAD_LDS16(base, L + tid * 16);               // hi plane 8K
        GLOAD_LDS16(base + 512, L + 8192 + tid * 16);  // lo plane 8K
    };
    auto stageB = [&](int tap, int cc, int buf) {
        char* L = sm + 32768 + buf * 32768;
        #pragma unroll
        for (int i = 0; i < 2; ++i) {
            const _Float16* bb =
                W2x + ((size_t)(tap * 256 + sBr[i])) * 512 + cc * 32 + sBq[i];
            GLOAD_LDS16(bb, L + sBs[i] * 16);                        // Bh 16K
            GLOAD_LDS16(bb + (size_t)9 * 256 * 512, L + 16384 + sBs[i] * 16);
        }
    };

    f32x4 acc[4][4];
    #pragma unroll
    for (int s = 0; s < 4; ++s)
        #pragma unroll
        for (int t = 0; t < 4; ++t)
            #pragma unroll
            for (int r = 0; r < 4; ++r) acc[s][t][r] = 0.f;

    stageA(cc0, 0);
    stageB(0, cc0, 0);
    const half8_t zfrag = {};
    int gi = 0;
    for (int cci = 0; cci < 8; ++cci) {
        int cc = cc0 + cci;
        const char* Ab = sm + (cci & 1) * 16384;
        for (int tap = 0; tap < 9; ++tap, ++gi) {
            __syncthreads();
            if (tap < 8) stageB(tap + 1, cc, (gi + 1) & 1);
            else if (cci < 7) stageB(0, cc + 1, (gi + 1) & 1);
            if (tap == 7 && cci < 7) stageA(cc + 1, (cci + 1) & 1);

            int dy = tap / 3 - 1, dx = tap - (tap / 3) * 3 - 1;
            half8_t ah[4], al[4];
            #pragma unroll
            for (int s = 0; s < 4; ++s) {
                int ih = ph[s] + dy, iw = pw[s] + dx;
                bool v = ((unsigned)ih < 8u) && ((unsigned)iw < 8u);
                int pp = imgoff[s] + (v ? ih * 8 + iw : 0);
                int ao = pp * 64 + ((fq ^ ((pp >> 1) & 3)) << 4);
                half8_t a0 = *(const half8_t*)(Ab + ao);
                half8_t a1 = *(const half8_t*)(Ab + 8192 + ao);
                ah[s] = v ? a0 : zfrag;
                al[s] = v ? a1 : zfrag;
            }
            const char* Bb = sm + 32768 + (gi & 1) * 32768;
            half8_t bh[4], bl[4];
            #pragma unroll
            for (int t = 0; t < 4; ++t) {
                bh[t] = *(const half8_t*)(Bb + boff[t]);
                bl[t] = *(const half8_t*)(Bb + 16384 + boff[t]);
            }
            #pragma unroll
            for (int s = 0; s < 4; ++s)
                #pragma unroll
                for (int t = 0; t < 4; ++t)
                    acc[s][t] = __builtin_amdgcn_mfma_f32_16x16x32_f16(
                        ah[s], bh[t], acc[s][t], 0, 0, 0);
            #pragma unroll
            for (int s = 0; s < 4; ++s)
                #pragma unroll
                for (int t = 0; t < 4; ++t)
                    acc[s][t] = __builtin_amdgcn_mfma_f32_16x16x32_f16(
                        ah[s], bl[t], acc[s][t], 0, 0, 0);
            #pragma unroll
            for (int s = 0; s < 4; ++s)
                #pragma unroll
                for (int t = 0; t < 4; ++t)
                    acc[s][t] = __builtin_amdgcn_mfma_f32_16x16x32_f16(
                        al[s], bh[t], acc[s][t], 0, 0, 0);
        }
    }

    // epilogue: z=0 -> yb (+bias); z=1 -> tmp (raw partial)
    float* dst = (z == 0) ? yb : tmp;
    float bv[4];
    #pragma unroll
    for (int t = 0; t < 4; ++t)
        bv[t] = (z == 0) ? b2[wn * 64 + t * 16 + fr] : 0.f;
    #pragma unroll
    for (int s = 0; s < 4; ++s)
        #pragma unroll
        for (int r = 0; r < 4; ++r) {
            int m = m0 + wm * 64 + s * 16 + fq * 4 + r;
            #pragma unroll
            for (int t = 0; t < 4; ++t) {
                int d = wn * 64 + t * 16 + fr;
                dst[(size_t)m * 256 + d] = acc[s][t][r] + bv[t];
            }
        }
}

// ---------------- fused post-conv pack: yb += tmp; A2<-yb; B2,esq<-emb -----
__global__ __launch_bounds__(256) void pack3_k(
    float* __restrict__ yb, const float* __restrict__ tmp,
    const float* __restrict__ emb,
    _Float16* __restrict__ A2, _Float16* __restrict__ B2,
    float* __restrict__ esq) {
    #pragma unroll
    for (int it = 0; it < 8; ++it) {
        int i = (blockIdx.x + it * 512) * 256 + threadIdx.x;
        float4 v = *(const float4*)(yb + (size_t)i * 4);
        float4 t = *(const float4*)(tmp + (size_t)i * 4);
        float4 s = {v.x + t.x, v.y + t.y, v.z + t.z, v.w + t.w};
        *(float4*)(yb + (size_t)i * 4) = s;
        half4_t h = {(_Float16)s.x, (_Float16)s.y, (_Float16)s.z, (_Float16)s.w};
        *(half4_t*)(A2 + (size_t)i * 4) = h;
    }
    int w = threadIdx.x >> 6, lane = threadIdx.x & 63;
    #pragma unroll
    for (int j = 0; j < 4; ++j) {
        int k = blockIdx.x * 16 + w * 4 + j;
        float4 v = *(const float4*)(emb + (size_t)k * 256 + lane * 4);
        half4_t h = {(_Float16)v.x, (_Float16)v.y, (_Float16)v.z, (_Float16)v.w};
        *(half4_t*)(B2 + (size_t)k * 256 + lane * 4) = h;
        float s = v.x * v.x + v.y * v.y + v.z * v.z + v.w * v.w;
        #pragma unroll
        for (int m = 32; m >= 1; m >>= 1) s += __shfl_xor(s, m, 64);
        if (lane == 0) esq[k] = s;
    }
}

// ---------------- MFMA screen v11: screen7 structure, 128x256 tile ---------
// (R15 winner verbatim: 145.5us fast-container, absmax 0) 1-D grid 4096,
// 512 thr = 8 waves (2 wm x 4 wn of 64x64). XCD-aware remap. LDS 48 KB
// dbuf -> 2 blocks/CU. colIdx = nt*4 + wn.
__global__ __launch_bounds__(512) void screen11_k(
    const _Float16* __restrict__ A2, const _Float16* __restrict__ B2,
    const float* __restrict__ esq, float* __restrict__ ps2, int* __restrict__ pi2) {
    __shared__ char sm[49152];
    int Lb = blockIdx.x;
    int xcd = Lb & 7, j = Lb >> 3;
    int mt = xcd * 16 + (j & 15);
    int nt = j >> 4;
    int m0 = mt * 128, n0 = nt * 256;
    int tid = threadIdx.x, w = tid >> 6, lane = tid & 63;
    int wm = w & 1, wn = w >> 1;
    int fr = lane & 15, fq = lane >> 4;

    int xq = (fq ^ ((fr >> 1) & 3)) << 4;
    int aoff[4], boff[4];
    #pragma unroll
    for (int i = 0; i < 4; ++i) {
        aoff[i] = (wm * 64 + i * 16 + fr) * 64 + xq;
        boff[i] = (wn * 64 + i * 16 + fr) * 64 + xq;
    }
    int sAr = tid >> 2, sAq = ((tid & 3) ^ ((tid >> 3) & 3)) * 8;
    int sBs[2], sBr[2], sBq[2];
    #pragma unroll
    for (int i = 0; i < 2; ++i) {
        int s = i * 512 + tid;
        sBs[i] = s;
        sBr[i] = s >> 2;
        sBq[i] = ((s & 3) ^ ((s >> 3) & 3)) * 8;
    }

    auto stage = [&](int kt, int buf) {
        char* L = sm + buf * 24576;
        int ko = kt * 32;
        GLOAD_LDS16(A2 + (size_t)(m0 + sAr) * 256 + ko + sAq, L + tid * 16);
        #pragma unroll
        for (int i = 0; i < 2; ++i)
            GLOAD_LDS16(B2 + (size_t)(n0 + sBr[i]) * 256 + ko + sBq[i],
                        L + 8192 + sBs[i] * 16);
    };

    f32x4 acc[4][4];
    #pragma unroll
    for (int s = 0; s < 4; ++s)
        #pragma unroll
        for (int t = 0; t < 4; ++t)
            #pragma unroll
            for (int r = 0; r < 4; ++r) acc[s][t][r] = 0.f;

    stage(0, 0);
    for (int kt = 0; kt < 8; ++kt) {
        __syncthreads();
        if (kt + 1 < 8) stage(kt + 1, (kt + 1) & 1);
        const char* L = sm + (kt & 1) * 24576;
        half8_t af[4], bf[4];
        #pragma unroll
        for (int s = 0; s < 4; ++s) af[s] = *(const half8_t*)(L + aoff[s]);
        #pragma unroll
        for (int t = 0; t < 4; ++t) bf[t] = *(const half8_t*)(L + 8192 + boff[t]);
        #pragma unroll
        for (int s = 0; s < 4; ++s)
            #pragma unroll
            for (int t = 0; t < 4; ++t)
                acc[s][t] = __builtin_amdgcn_mfma_f32_16x16x32_f16(
                    af[s], bf[t], acc[s][t], 0, 0, 0);
    }

    float esv[4];
    #pragma unroll
    for (int t = 0; t < 4; ++t) esv[t] = esq[n0 + wn * 64 + t * 16 + fr];
    int colIdx = nt * 4 + wn;
    #pragma unroll
    for (int s = 0; s < 4; ++s) {
        #pragma unroll
        for (int r = 0; r < 4; ++r) {
            float best = 3.4e38f; int bidx = 0x7fffffff;
            #pragma unroll
            for (int t = 0; t < 4; ++t) {
                float sc = esv[t] - 2.f * acc[s][t][r];
                int k = n0 + wn * 64 + t * 16 + fr;
                if (sc < best || (sc == best && k < bidx)) { best = sc; bidx = k; }
            }
            #pragma unroll
            for (int msk = 1; msk <= 8; msk <<= 1) {
                float so = __shfl_xor(best, msk, 64);
                int ko2 = __shfl_xor(bidx, msk, 64);
                if (so < best || (so == best && ko2 < bidx)) { best = so; bidx = ko2; }
            }
            if (fr == 0) {
                int m = m0 + wm * 64 + s * 16 + fq * 4 + r;
                ps2[(size_t)m * 128 + colIdx] = best;
                pi2[(size_t)m * 128 + colIdx] = bidx;
            }
        }
    }
}

// ---------------- exact fp32 refine, grid-stride (512 blocks) ----------------
__global__ __launch_bounds__(256) void refine3_k(
    const float* __restrict__ y, const float* __restrict__ emb,
    const float* __restrict__ esq, const float* __restrict__ ps2,
    const int* __restrict__ pi2, int* __restrict__ out) {
    int lane = threadIdx.x & 63;
    for (int j = 0; j < 8; ++j) {
        int m = blockIdx.x * 32 + j * 4 + (threadIdx.x >> 6);
        float4 yv = *(const float4*)(y + (size_t)m * 256 + lane * 4);
        float sc_[2]; int kc_[2];
        #pragma unroll
        for (int i = 0; i < 2; ++i) {
            sc_[i] = ps2[(size_t)m * 128 + lane * 2 + i];
            kc_[i] = pi2[(size_t)m * 128 + lane * 2 + i];
        }
        float s0 = fminf(sc_[0], sc_[1]);
        #pragma unroll
        for (int msk = 1; msk <= 32; msk <<= 1) s0 = fminf(s0, __shfl_xor(s0, msk, 64));
        float thr = s0 + 0.25f;
        float best = 3.4e38f; int bk = 0x7fffffff;
        for (int c = 0; c < 128; ++c) {
            float scc = __shfl(sc_[c & 1], c >> 1, 64);
            if (scc <= thr) {            // wave-uniform
                int k = __shfl(kc_[c & 1], c >> 1, 64);
                float4 ev = *(const float4*)(emb + (size_t)k * 256 + lane * 4);
                float d = yv.x * ev.x + yv.y * ev.y + yv.z * ev.z + yv.w * ev.w;
                #pragma unroll
                for (int msk = 1; msk <= 32; msk <<= 1) d += __shfl_xor(d, msk, 64);
                float sx = esq[k] - 2.f * d;
                if (sx < best || (sx == best && k < bk)) { best = sx; bk = k; }
            }
        }
        if (lane == 0) out[m] = bk;
    }
}

extern "C" void kernel_launch(void* const* d_in, const int* in_sizes, int n_in,
                              void* d_out, int out_size, void* d_ws, size_t ws_size,
                              hipStream_t stream) {
    const float* latent = (const float*)d_in[0];
    const float* conv_w = (const float*)d_in[1];
    const float* conv_b = (const float*)d_in[2];
    const float* lin_w  = (const float*)d_in[3];
    const float* lin_b  = (const float*)d_in[4];
    const float* emb    = (const float*)d_in[5];
    int* out = (int*)d_out;

    char* W = (char*)d_ws;                           // proven 55.35 MB budget
    float*    b2  = (float*)(W + 262144);            //     1,024
    float*    esq = (float*)(W + 263168);            //    32,768
    float*    yb  = (float*)(W + 295936);            // 16,777,216
    _Float16* W2x = (_Float16*)(W + 17073152);       //  4,718,592
    _Float16* Xnp = (_Float16*)(W + 21792768);       // 33,554,432 (live: prep -> convm10)
    // post-conv aliases on the (dead) Xnp region:
    _Float16* A2  = (_Float16*)(W + 21792768);       //  8,388,608 (pack3 -> screen11)
    _Float16* B2  = (_Float16*)(W + 30181376);       //  4,194,304 (pack3 -> screen11)
    float*    ps2 = (float*)(W + 34375680);          //  8,388,608 (screen11 -> refine3)
    int*      pi2 = (int*)(W + 42764288);            //  8,388,608 -> ends 51,152,896
    // conv partial-sum half 2: occupies the (pre-screen dead) ps2+pi2 span
    float*    tmp = (float*)(W + 34375680);          // 16,777,216 (convm10 -> pack3)

    prep_k<<<833, 256, 0, stream>>>(latent, lin_w, conv_w, conv_b, lin_b,
                                    Xnp, W2x, b2);
    convm10_k<<<256, 512, 0, stream>>>(Xnp, W2x, b2, yb, tmp);
    pack3_k<<<512, 256, 0, stream>>>(yb, tmp, emb, A2, B2, esq);  // Xnp, tmp dead after
    screen11_k<<<4096, 512, 0, stream>>>(A2, B2, esq, ps2, pi2);
    refine3_k<<<512, 256, 0, stream>>>(yb, emb, esq, ps2, pi2, out);
}